// Round 2
// baseline (337.715 us; speedup 1.0000x reference)
//
#include <hip/hip_runtime.h>
#include <cstdint>
#include <cstddef>

typedef _Float16 f16;
typedef _Float16 f16x8 __attribute__((ext_vector_type(8)));
typedef float f32x4 __attribute__((ext_vector_type(4)));

#define AS1 __attribute__((address_space(1)))
#define AS3 __attribute__((address_space(3)))

// async 16B global->LDS, per-lane source addr, LDS dst = wave-uniform base + lane*16
__device__ __forceinline__ void gl_lds16(const void* g, void* l) {
  __builtin_amdgcn_global_load_lds((AS1 void*)g, (AS3 void*)l, 16u, 0, 0u);
}

// c_tab[parity][a(tap)][i(conv-weight idx)] — folded FIR/upsample coefficients
__constant__ float c_tab[2][3][3] = {
  {{0.75f, 0.25f, 0.00f}, {0.25f, 0.75f, 0.75f}, {0.00f, 0.00f, 0.25f}},
  {{0.25f, 0.00f, 0.00f}, {0.75f, 0.75f, 0.25f}, {0.00f, 0.25f, 0.75f}}
};

// =====================================================================================
// Fused prep (unchanged):
//  blocks [0,256):        build Et3[c8][ay3][ax3][jj1024][ic32] f16 from W (f32)
//  blocks [256,256+4224): fill Ah[n8][y66][x66][ic256] f16 (NCHW->NHWC + zeroed halo)
// =====================================================================================
__global__ __launch_bounds__(256) void prep_k(const float* __restrict__ W,
                                              const float* __restrict__ In,
                                              f16* __restrict__ Et,
                                              f16* __restrict__ Ah) {
  const int b = blockIdx.x;
  const int tid = threadIdx.x;
  if (b < 256) {
    // ---- Et3 build ----
    const int oc = b;
    const int ic = tid;
    const int c = ic >> 5, icl = ic & 31;
    float w[9];
    const float* wp = W + ((size_t)oc * 256 + ic) * 9;
#pragma unroll
    for (int t = 0; t < 9; ++t) w[t] = wp[t];
#pragma unroll
    for (int py = 0; py < 2; ++py)
#pragma unroll
      for (int px = 0; px < 2; ++px) {
        const int jj = oc * 4 + py * 2 + px;
#pragma unroll
        for (int ay = 0; ay < 3; ++ay)
#pragma unroll
          for (int ax = 0; ax < 3; ++ax) {
            float s = 0.f;
#pragma unroll
            for (int iy = 0; iy < 3; ++iy)
#pragma unroll
              for (int ix = 0; ix < 3; ++ix)
                s += w[iy * 3 + ix] * c_tab[py][ay][iy] * c_tab[px][ax][ix];
            Et[((size_t)(((c * 3 + ay) * 3 + ax) * 1024 + jj)) * 32 + icl] = (f16)s;
          }
      }
  } else {
    // ---- Ah fill ----
    const int bid2 = b - 256;
    const int icc = bid2 & 7;
    const int v = bid2 >> 3;       // 0..527
    const int n = v / 66;
    const int yp = v - n * 66;     // y' in 0..65
    const int ic0 = icc * 32;
    const int icl = tid & 31, x8 = tid >> 5;
    f16* rowbase = Ah + ((size_t)(n * 66 + yp) * 66) * 256 + ic0;
    if (yp == 0 || yp == 65) {
      // full halo row -> zeros
#pragma unroll
      for (int i = 0; i < 9; ++i) {
        const int xp = i * 8 + x8;
        if (xp < 66) rowbase[(size_t)xp * 256 + icl] = (f16)0.f;
      }
    } else {
      const int y = yp - 1;
      __shared__ float tile[32][65];  // +1 pad: write-phase stride-65 reads, no conflicts
      const int xl = tid & 63, icl4 = tid >> 6;
      const float* src = In + (((size_t)(n * 256 + ic0)) * 64 + y) * 64;
#pragma unroll
      for (int i = 0; i < 8; ++i) {
        const int icl_ = i * 4 + icl4;
        tile[icl_][xl] = src[(size_t)icl_ * 4096 + xl];
      }
      __syncthreads();
      f16* dst = rowbase + 256;  // x'=1
#pragma unroll
      for (int i = 0; i < 8; ++i) {
        const int x = i * 8 + x8;
        dst[(size_t)x * 256 + icl] = (f16)tile[icl][x];
      }
      if (x8 == 0) {  // halo columns x'=0 and x'=65
        rowbase[icl] = (f16)0.f;
        rowbase[(size_t)65 * 256 + icl] = (f16)0.f;
      }
    }
  }
}

// =====================================================================================
// Implicit-GEMM conv: M=32768 x N=1024, K = 8 ic-chunks x 3 ay x (3 ax x 32 ic).
// 24 stages, double-buffered LDS, bank-conflict-free XOR swizzle (round 1, verified 0
// conflicts). NEW this round — T4 counted-vmcnt pipeline (raw barriers, no vmcnt(0)
// drain in the main loop):
//   A: issue prefetch(t+1) -> buf[p^1]   (uniform 9 gl_lds per wave)
//   B: s_waitcnt vmcnt(9)                 <- drains stage-t loads (issued LAST iter,
//                                            a full stage of latency cover); t+1's 9
//                                            stay in flight across both barriers
//   C: s_barrier                          (buf[p] writes visible from all waves)
//   D: ds_read frags(buf[p]); s_waitcnt lgkmcnt(0)
//   F: s_barrier                          (all reads done before next iter overwrites)
//   G: 48 MFMAs
// __syncthreads (which compiles to a vmcnt(0)+lgkmcnt(0) drain) appears nowhere in
// the loop. The A-tail (256 B) is split 4 ways (lanes 0-3 of each wave) so every wave
// issues exactly 9 loads/stage -> one literal vmcnt(9) works for all waves.
// =====================================================================================
__global__ __launch_bounds__(256) void gemm_k(const f16* __restrict__ Ah,
                                              const f16* __restrict__ Et,
                                              const float* __restrict__ bias,
                                              float* __restrict__ out) {
  __shared__ __align__(256) f16 lA[2][4224];   // [buf][r2][x66][ic32]    2 x 8448 B
  __shared__ __align__(256) f16 lB[2][12288];  // [buf][ax3][jj128][ic32] 2 x 24576 B
  const int tid = threadIdx.x;
  const int wave = tid >> 6;
  const int lane = tid & 63;
  const int bid = blockIdx.x;  // 2048 = 256 mt * 8 nt; nt fastest -> Et slice per-XCD L2-hot
  const int nt = bid & 7;
  const int mt = bid >> 3;
  const int m0 = mt * 128;
  const int jj0 = nt * 128;
  const int n = m0 >> 12;
  const int y0 = (m0 >> 6) & 63;  // even, 0..62; tile covers y0,y0+1 (x full 0..63)

  // ---- staging per-lane constants (fixed across stages) ----
  // hig: source-side companion of the read swizzle (granule bits[1:0] ^= lane bits[4:3]).
  const int hig = (lane & 3) ^ ((lane >> 3) & 3);
  int goA[2];
#pragma unroll
  for (int i = 0; i < 2; ++i) {
    const int s = wave * 2 + i;
    const int u = s * 16 + (lane >> 2);
    const int row = (u >= 66) ? 1 : 0;
    const int x = u - 66 * row;
    goA[i] = ((row * 66 + x) * 256 + hig * 8) * 2;  // bytes into Ah from stage base
  }
  // distributed A-tail: wave w stages x-unit u=128+w (row1, x=62+w) with lanes 0..3.
  // LDS dst byte = 8192 + w*64 + lane*16 -> bits[8:7] = w>>1, bits[5:4] = lane
  // -> source granule must be lane ^ (w>>1) to match the read-side XOR swizzle.
  const int goAt = ((66 + 62 + wave) * 256 + (((lane ^ (wave >> 1)) & 3)) * 8) * 2;
  int goB[6];
#pragma unroll
  for (int j = 0; j < 6; ++j) {
    const int t = wave + 4 * j;
    const int ax = t >> 3, sub = t & 7;
    goB[j] = (ax * 32768 + (sub * 16 + (lane >> 2)) * 32 + hig * 8) * 2;
  }
  char* const lAb = (char*)lA;
  char* const lBb = (char*)lB;

  // ---- compute-side: swizzled, stage-invariant LDS read offsets (kept in regs) ----
  const int wm = wave >> 1, wn = wave & 1;  // 2x2 wave grid, each 64(m) x 64(jj)
  const int lr = lane & 15;
  const int hi16 = (lane >> 4) * 16;
  int rdA[4][3];
#pragma unroll
  for (int mi = 0; mi < 4; ++mi)
#pragma unroll
    for (int ax = 0; ax < 3; ++ax) {
      const int o = wm * 4224 + (lr + mi * 16 + ax) * 64 + hi16;
      rdA[mi][ax] = o ^ (((o >> 7) & 3) << 4);
    }
  int rdB[4][3];
#pragma unroll
  for (int ni = 0; ni < 4; ++ni)
#pragma unroll
    for (int ax = 0; ax < 3; ++ax) {
      const int o = (wn * 64 + lr) * 64 + hi16 + ax * 8192 + ni * 1024;
      rdB[ni][ax] = o ^ (((o >> 7) & 3) << 4);
    }

  const char* const aN = (const char*)Ah + (size_t)(n * 66 + y0) * 33792;  // 66*256*2 per y
  const char* const bE = (const char*)Et + (size_t)jj0 * 64;               // jj0*32*2

  const f32x4 vzero = {0.f, 0.f, 0.f, 0.f};
  f32x4 acc[4][4];
#pragma unroll
  for (int i = 0; i < 4; ++i)
#pragma unroll
    for (int j = 0; j < 4; ++j) acc[i][j] = vzero;

  // ---- prologue: issue stage 0 (c=0,ay=0) into buffer 0; NO wait here — iter 0's
  //      counted vmcnt(9) (after issuing stage 1) is the first drain point.
  {
    gl_lds16(aN + goA[0], lAb + (wave * 2 + 0) * 1024);
    gl_lds16(aN + goA[1], lAb + (wave * 2 + 1) * 1024);
    if (lane < 4) gl_lds16(aN + goAt, lAb + 8192 + wave * 64);
#pragma unroll
    for (int j = 0; j < 6; ++j) gl_lds16(bE + goB[j], lBb + (wave + 4 * j) * 1024);
  }

  const char* aPn = aN + 33792;    // next-stage (t=1: c=0, ay=1) source pointers
  const char* bPn = bE + 196608;   // 98304 f16 per (c,ay)
  int ayn = 1;

#pragma unroll 1
  for (int t = 0; t < 24; ++t) {
    const int p = t & 1;

    // A: prefetch stage t+1 into the other buffer (its last readers were fenced by
    //    iter t-1's second barrier). Then B: counted wait — never vmcnt(0) mid-loop.
    if (t < 23) {
      char* dA = lAb + (p ^ 1) * 8448;
      char* dB = lBb + (p ^ 1) * 24576;
      gl_lds16(aPn + goA[0], dA + (wave * 2 + 0) * 1024);
      gl_lds16(aPn + goA[1], dA + (wave * 2 + 1) * 1024);
      if (lane < 4) gl_lds16(aPn + goAt, dA + 8192 + wave * 64);
#pragma unroll
      for (int j = 0; j < 6; ++j) gl_lds16(bPn + goB[j], dB + (wave + 4 * j) * 1024);
      bPn += 196608;
      if (ayn == 2) { aPn -= 67520; ayn = 0; }  // ay wrap: += 64 - 2*33792 (c++)
      else          { aPn += 33792; ++ayn; }
      asm volatile("s_waitcnt vmcnt(9)" ::: "memory");
    } else {
      asm volatile("s_waitcnt vmcnt(0)" ::: "memory");  // final stage: nothing newer
    }
    // C: all waves' stage-t writes into buf[p] are complete & visible past this point.
    __builtin_amdgcn_s_barrier();
    __builtin_amdgcn_sched_barrier(0);

    // D: all fragments of this stage -> registers
    const char* sA = lAb + p * 8448;
    const char* sB = lBb + p * 24576;
    f16x8 af[3][4], bf[3][4];
#pragma unroll
    for (int ax = 0; ax < 3; ++ax) {
#pragma unroll
      for (int mi = 0; mi < 4; ++mi) af[ax][mi] = *(const f16x8*)(sA + rdA[mi][ax]);
#pragma unroll
      for (int ni = 0; ni < 4; ++ni) bf[ax][ni] = *(const f16x8*)(sB + rdB[ni][ax]);
    }
    // E+F: own reads drained, then fence so next iter's prefetch may overwrite buf[p].
    asm volatile("s_waitcnt lgkmcnt(0)" ::: "memory");
    __builtin_amdgcn_sched_barrier(0);
    __builtin_amdgcn_s_barrier();

    // G: MFMAs — overlap with other waves' next-iter prefetch issue & in-flight loads.
#pragma unroll
    for (int ax = 0; ax < 3; ++ax)
#pragma unroll
      for (int mi = 0; mi < 4; ++mi)
#pragma unroll
        for (int ni = 0; ni < 4; ++ni)
          acc[mi][ni] = __builtin_amdgcn_mfma_f32_16x16x32_f16(af[ax][mi], bf[ax][ni],
                                                               acc[mi][ni], 0, 0, 0);
  }

  // ---- epilogue: C layout col=lane&15 (jj), row=(lane>>4)*4+v (m) ----
  const int yw = y0 + wm;
#pragma unroll
  for (int ni = 0; ni < 4; ++ni) {
    const int jj = jj0 + wn * 64 + ni * 16 + lr;
    const int oc = jj >> 2;
    const int py = (jj >> 1) & 1, px = jj & 1;
    const float bv = bias[oc];
    const int oy = 2 * yw + py;
    float* orow = out + ((size_t)(n * 256 + oc) * 128 + oy) * 128;
#pragma unroll
    for (int mi = 0; mi < 4; ++mi) {
      const int xb = mi * 16 + ((lane >> 4) << 2);
#pragma unroll
      for (int v = 0; v < 4; ++v) {
        orow[2 * (xb + v) + px] = acc[mi][ni][v] + bv;
      }
    }
  }
}

// ---------------- fallback (ws too small): direct, slow, correct ---------------------
__global__ __launch_bounds__(256) void fallback_k(const float* __restrict__ In,
                                                  const float* __restrict__ W,
                                                  const float* __restrict__ bias,
                                                  float* __restrict__ out) {
  const size_t idx = (size_t)blockIdx.x * 256 + threadIdx.x;
  const int ox = (int)(idx & 127), oy = (int)((idx >> 7) & 127);
  const int oc = (int)((idx >> 14) & 255);
  const int n = (int)(idx >> 22);
  const int px = ox & 1, py = oy & 1;
  const int x = ox >> 1, y = oy >> 1;
  float cy[3][3], cx[3][3];
#pragma unroll
  for (int a = 0; a < 3; ++a)
#pragma unroll
    for (int i = 0; i < 3; ++i) {
      cy[a][i] = c_tab[py][a][i];
      cx[a][i] = c_tab[px][a][i];
    }
  float acc = 0.f;
  const float* wbase = W + (size_t)oc * 2304;
  for (int ic = 0; ic < 256; ++ic) {
    const float* ib = In + (((size_t)(n * 256 + ic)) * 64 + y) * 64 + x;
    float pin[3][3];
#pragma unroll
    for (int ay = 0; ay < 3; ++ay) {
      const int yy = y + ay - 1;
#pragma unroll
      for (int ax = 0; ax < 3; ++ax) {
        const int xx = x + ax - 1;
        pin[ay][ax] = (yy >= 0 && yy < 64 && xx >= 0 && xx < 64)
                          ? ib[(ay - 1) * 64 + (ax - 1)] : 0.f;
      }
    }
    const float* w = wbase + ic * 9;
    float U[3][3];
#pragma unroll
    for (int ay = 0; ay < 3; ++ay)
#pragma unroll
      for (int ix = 0; ix < 3; ++ix)
        U[ay][ix] = cx[0][ix] * pin[ay][0] + cx[1][ix] * pin[ay][1] + cx[2][ix] * pin[ay][2];
#pragma unroll
    for (int iy = 0; iy < 3; ++iy)
#pragma unroll
      for (int ix = 0; ix < 3; ++ix) {
        const float V = cy[0][iy] * U[0][ix] + cy[1][iy] * U[1][ix] + cy[2][iy] * U[2][ix];
        acc += w[iy * 3 + ix] * V;
      }
  }
  out[idx] = acc + bias[oc];
}

extern "C" void kernel_launch(void* const* d_in, const int* in_sizes, int n_in,
                              void* d_out, int out_size, void* d_ws, size_t ws_size,
                              hipStream_t stream) {
  const float* In = (const float*)d_in[0];    // [8][256][64][64]
  const float* W = (const float*)d_in[1];     // [256][256][3][3]
  const float* bias = (const float*)d_in[2];  // [256]
  float* out = (float*)d_out;                 // [8][256][128][128]

  const size_t E_BYTES = (size_t)1024 * 2304 * 2;       // 4,718,592
  const size_t A_BYTES = (size_t)8 * 66 * 66 * 256 * 2; // 17,842,176

  if (ws_size >= E_BYTES + A_BYTES) {
    f16* Et = (f16*)d_ws;
    f16* Ah = (f16*)((char*)d_ws + E_BYTES);
    prep_k<<<256 + 4224, 256, 0, stream>>>(W, In, Et, Ah);
    gemm_k<<<2048, 256, 0, stream>>>(Ah, Et, bias, out);
  } else {
    fallback_k<<<131072, 256, 0, stream>>>(In, W, bias, out);
  }
}

// Round 3
// 322.518 us; speedup vs baseline: 1.0471x; 1.0471x over previous
//
#include <hip/hip_runtime.h>
#include <cstdint>
#include <cstddef>

typedef _Float16 f16;
typedef _Float16 f16x8 __attribute__((ext_vector_type(8)));
typedef float f32x4 __attribute__((ext_vector_type(4)));

#define AS1 __attribute__((address_space(1)))
#define AS3 __attribute__((address_space(3)))

// async 16B global->LDS, per-lane source addr, LDS dst = wave-uniform base + lane*16
__device__ __forceinline__ void gl_lds16(const void* g, void* l) {
  __builtin_amdgcn_global_load_lds((AS1 void*)g, (AS3 void*)l, 16u, 0, 0u);
}

// c_tab[parity][a(tap)][i(conv-weight idx)] — folded FIR/upsample coefficients
__constant__ float c_tab[2][3][3] = {
  {{0.75f, 0.25f, 0.00f}, {0.25f, 0.75f, 0.75f}, {0.00f, 0.00f, 0.25f}},
  {{0.25f, 0.00f, 0.00f}, {0.75f, 0.75f, 0.25f}, {0.00f, 0.25f, 0.75f}}
};

// =====================================================================================
// Fused prep (unchanged):
//  blocks [0,256):        build Et3[c8][ay3][ax3][jj1024][ic32] f16 from W (f32)
//  blocks [256,256+4224): fill Ah[n8][y66][x66][ic256] f16 (NCHW->NHWC + zeroed halo)
// =====================================================================================
__global__ __launch_bounds__(256) void prep_k(const float* __restrict__ W,
                                              const float* __restrict__ In,
                                              f16* __restrict__ Et,
                                              f16* __restrict__ Ah) {
  const int b = blockIdx.x;
  const int tid = threadIdx.x;
  if (b < 256) {
    // ---- Et3 build ----
    const int oc = b;
    const int ic = tid;
    const int c = ic >> 5, icl = ic & 31;
    float w[9];
    const float* wp = W + ((size_t)oc * 256 + ic) * 9;
#pragma unroll
    for (int t = 0; t < 9; ++t) w[t] = wp[t];
#pragma unroll
    for (int py = 0; py < 2; ++py)
#pragma unroll
      for (int px = 0; px < 2; ++px) {
        const int jj = oc * 4 + py * 2 + px;
#pragma unroll
        for (int ay = 0; ay < 3; ++ay)
#pragma unroll
          for (int ax = 0; ax < 3; ++ax) {
            float s = 0.f;
#pragma unroll
            for (int iy = 0; iy < 3; ++iy)
#pragma unroll
              for (int ix = 0; ix < 3; ++ix)
                s += w[iy * 3 + ix] * c_tab[py][ay][iy] * c_tab[px][ax][ix];
            Et[((size_t)(((c * 3 + ay) * 3 + ax) * 1024 + jj)) * 32 + icl] = (f16)s;
          }
      }
  } else {
    // ---- Ah fill ----
    const int bid2 = b - 256;
    const int icc = bid2 & 7;
    const int v = bid2 >> 3;       // 0..527
    const int n = v / 66;
    const int yp = v - n * 66;     // y' in 0..65
    const int ic0 = icc * 32;
    const int icl = tid & 31, x8 = tid >> 5;
    f16* rowbase = Ah + ((size_t)(n * 66 + yp) * 66) * 256 + ic0;
    if (yp == 0 || yp == 65) {
      // full halo row -> zeros
#pragma unroll
      for (int i = 0; i < 9; ++i) {
        const int xp = i * 8 + x8;
        if (xp < 66) rowbase[(size_t)xp * 256 + icl] = (f16)0.f;
      }
    } else {
      const int y = yp - 1;
      __shared__ float tile[32][65];  // +1 pad: write-phase stride-65 reads, no conflicts
      const int xl = tid & 63, icl4 = tid >> 6;
      const float* src = In + (((size_t)(n * 256 + ic0)) * 64 + y) * 64;
#pragma unroll
      for (int i = 0; i < 8; ++i) {
        const int icl_ = i * 4 + icl4;
        tile[icl_][xl] = src[(size_t)icl_ * 4096 + xl];
      }
      __syncthreads();
      f16* dst = rowbase + 256;  // x'=1
#pragma unroll
      for (int i = 0; i < 8; ++i) {
        const int x = i * 8 + x8;
        dst[(size_t)x * 256 + icl] = (f16)tile[icl][x];
      }
      if (x8 == 0) {  // halo columns x'=0 and x'=65
        rowbase[icl] = (f16)0.f;
        rowbase[(size_t)65 * 256 + icl] = (f16)0.f;
      }
    }
  }
}

// =====================================================================================
// Implicit-GEMM conv, 256x256-tile 8-wave phase-interleaved schedule (m201-style).
//   M=32768 (n,y,x) x N=1024 (jj) x K=2304, consumed as 24 stages (c,ay) of 3 ax-
//   phases (K=32 ic each). Block tile 256m x 256jj, 512 threads = 8 waves (2m x 4n),
//   wave tile 128x64 -> FLOP/LDS-byte 42.7 (was 32 at 64x64 waves).
//   LDS 132 KB: A dbuf [r4][x66][ic32] (16.9 KB ea) + B dbuf [ax3][jj256][ic32]
//   (49.2 KB ea). 1 block/CU, 2 waves/SIMD.
// Per stage t: 3 phases (ax=0,1,2), each:
//   {12 ds_read_b128 (8 A + 4 B) | phase0: issue all 9 gl_lds for t+1 into buf^1}
//   -> s_barrier -> lgkmcnt(0)+sched_barrier -> setprio(1) -> 32 MFMA -> setprio(0)
//   -> [phase2: vmcnt(0), ~full stage of cover, nothing newer in flight] -> s_barrier
// Bank-conflict-free XOR swizzle (verified 0 conflicts, round 1): read byte offsets
//   o ^= ((o>>7)&3)<<4; staging keeps LDS linear and pre-swizzles the per-lane GLOBAL
//   source granule (hig / tail-XOR). Both-sides involution verified algebraically.
// =====================================================================================
__global__ __launch_bounds__(512, 2) void gemm_k(const f16* __restrict__ Ah,
                                                 const f16* __restrict__ Et,
                                                 const float* __restrict__ bias,
                                                 float* __restrict__ out) {
  __shared__ __align__(256) f16 lA[2][8448];   // [buf][r4][x66][ic32]    2 x 16896 B
  __shared__ __align__(256) f16 lB[2][24576];  // [buf][ax3][jj256][ic32] 2 x 49152 B
  const int tid = threadIdx.x;
  const int wave = tid >> 6;     // 0..7
  const int lane = tid & 63;
  // XCD-aware bijective swizzle: 512 blocks, 512%8==0 -> each XCD gets 64 contiguous
  // logical ids = 16 mt x 4 nt (shared Et slices L2-hot per XCD).
  const int bid = (blockIdx.x & 7) * 64 + (blockIdx.x >> 3);
  const int nt = bid & 3;        // 4 jj-tiles of 256
  const int mt = bid >> 2;       // 128 m-tiles of 256
  const int m0 = mt * 256;
  const int jj0 = nt * 256;
  const int n = m0 >> 12;            // 4096 m per image, 16 tiles per image
  const int y0 = (m0 >> 6) & 63;     // 0,4,8,..,60; tile covers y0..y0+3, x 0..63

  // ---- staging per-lane constants (stage-invariant) ----
  // hig: source-side companion of the read swizzle (granule bits[1:0] ^= dst bits[8:7]
  // of the linear LDS destination = (lane>>3)&3 for 1KB-aligned slots).
  const int hig = (lane & 3) ^ ((lane >> 3) & 3);
  // A: 16896 B = 16 x 1KB slots (2 per wave) + 512 B tail (4 lanes x 8 waves).
  int goA[2];
#pragma unroll
  for (int i = 0; i < 2; ++i) {
    const int s = wave * 2 + i;            // slot 0..15
    const int u = s * 16 + (lane >> 2);    // x-unit 0..255 of [r4][x66]
    const int r = u / 66;
    const int xi = u - r * 66;
    goA[i] = r * 33792 + xi * 512 + hig * 16;  // bytes from stage base (Ah row=33792 B)
  }
  // tail: x-units 256..263 -> r=3, xi=58+wave; dst = 16384 + wave*64 + lane*16
  // (lanes 0..3) -> dst bits[8:7] = (wave>>1)&3 -> source granule lane ^ (wave>>1).
  const int goAt = 3 * 33792 + (58 + wave) * 512 + ((lane ^ (wave >> 1)) & 3) * 16;
  // B: 48 x 1KB slots; slot t = wave + 8*j: ax = t>>4, 16-jj sub-slab = t&15.
  int goB[6];
#pragma unroll
  for (int j = 0; j < 6; ++j) {
    const int t = wave + 8 * j;
    const int ax = t >> 4, jsl = t & 15;
    goB[j] = ax * 65536 + (jsl * 16 + (lane >> 2)) * 64 + hig * 16;  // Et ax-slab 65536 B
  }
  char* const lAb = (char*)lA;
  char* const lBb = (char*)lB;

  // ---- compute-side per-lane constants ----
  const int wm = wave >> 2, wn = wave & 3;  // 2m x 4n wave grid; wave tile 128m x 64jj
  const int lr = lane & 15;
  const int hi16 = (lane >> 4) * 16;
  // A fragment mi=0..7: m = wm*128 + mi*16 + frag-row; my = wm*2 + (mi>>2),
  // x = (mi&3)*16 + lr; LDS row-unit = my*66 + x (+ax at use).
  int rdA0[8];
#pragma unroll
  for (int mi = 0; mi < 8; ++mi)
    rdA0[mi] = ((wm * 2 + (mi >> 2)) * 66 + (mi & 3) * 16 + lr) * 64 + hi16;  // unswizzled
  // B fragment ni=0..3 (ax=0, pre-swizzled; +ax*16384 preserves bits[8:0] -> still valid)
  int rdBs[4];
#pragma unroll
  for (int ni = 0; ni < 4; ++ni) {
    const int o = (wn * 64 + ni * 16 + lr) * 64 + hi16;
    rdBs[ni] = o ^ (((o >> 7) & 3) << 4);
  }

  const char* const aBase = (const char*)Ah + ((size_t)(n * 66) + y0) * 33792;
  const char* const bE = (const char*)Et + (size_t)jj0 * 64;

  const f32x4 vzero = {0.f, 0.f, 0.f, 0.f};
  f32x4 acc[8][4];
#pragma unroll
  for (int i = 0; i < 8; ++i)
#pragma unroll
    for (int j = 0; j < 4; ++j) acc[i][j] = vzero;

  // ---- prologue: stage 0 (c=0,ay=0) into buffer 0; one drain (cold, ~free) ----
  {
    gl_lds16(aBase + goA[0], lAb + (wave * 2 + 0) * 1024);
    gl_lds16(aBase + goA[1], lAb + (wave * 2 + 1) * 1024);
    if (lane < 4) gl_lds16(aBase + goAt, lAb + 16384 + wave * 64);
#pragma unroll
    for (int j = 0; j < 6; ++j) gl_lds16(bE + goB[j], lBb + (wave + 8 * j) * 1024);
  }
  asm volatile("s_waitcnt vmcnt(0)" ::: "memory");
  __builtin_amdgcn_s_barrier();

  const char* aPn = aBase + 33792;   // stage 1 sources (c=0, ay=1)
  const char* bPn = bE + 196608;     // (c*3+ay) stride in Et3
  int ayn = 1;

#pragma unroll 1
  for (int t = 0; t < 24; ++t) {
    const int p = t & 1;
    const char* sA = lAb + p * 16896;
    const char* sB = lBb + p * 49152;

#pragma unroll
    for (int ax = 0; ax < 3; ++ax) {
      // --- fragment reads for this phase (buf[p]; conflict-free swizzled) ---
      f16x8 af[8], bf[4];
#pragma unroll
      for (int mi = 0; mi < 8; ++mi) {
        const int oa = rdA0[mi] + ax * 64;
        const int sw = oa ^ (((oa >> 7) & 3) << 4);
        af[mi] = *(const f16x8*)(sA + sw);
      }
#pragma unroll
      for (int ni = 0; ni < 4; ++ni)
        bf[ni] = *(const f16x8*)(sB + ax * 16384 + rdBs[ni]);

      // --- phase 0: issue ALL of stage t+1's 9 loads into buf[p^1] (freed by stage
      //     t-1's last barrier). Drained by phase-2's vmcnt(0): full stage of cover. ---
      if (ax == 0 && t < 23) {
        char* dA = lAb + (p ^ 1) * 16896;
        char* dB = lBb + (p ^ 1) * 49152;
        gl_lds16(aPn + goA[0], dA + (wave * 2 + 0) * 1024);
        gl_lds16(aPn + goA[1], dA + (wave * 2 + 1) * 1024);
        if (lane < 4) gl_lds16(aPn + goAt, dA + 16384 + wave * 64);
#pragma unroll
        for (int j = 0; j < 6; ++j) gl_lds16(bPn + goB[j], dB + (wave + 8 * j) * 1024);
        bPn += 196608;
        if (ayn == 2) { aPn -= 67520; ayn = 0; }  // c++: +64 B (ic), -2 rows (ay wrap)
        else          { aPn += 33792; ++ayn; }
      }

      __builtin_amdgcn_s_barrier();
      asm volatile("s_waitcnt lgkmcnt(0)" ::: "memory");
      __builtin_amdgcn_sched_barrier(0);

      __builtin_amdgcn_s_setprio(1);
#pragma unroll
      for (int mi = 0; mi < 8; ++mi)
#pragma unroll
        for (int ni = 0; ni < 4; ++ni)
          acc[mi][ni] = __builtin_amdgcn_mfma_f32_16x16x32_f16(af[mi], bf[ni],
                                                               acc[mi][ni], 0, 0, 0);
      __builtin_amdgcn_s_setprio(0);

      if (ax == 2 && t < 23) asm volatile("s_waitcnt vmcnt(0)" ::: "memory");
      __builtin_amdgcn_s_barrier();
    }
  }

  // ---- epilogue: C frag layout col=lane&15 (jj), row=(lane>>4)*4+v (m) ----
#pragma unroll
  for (int ni = 0; ni < 4; ++ni) {
    const int jj = jj0 + wn * 64 + ni * 16 + lr;
    const int oc = jj >> 2;
    const int py = (jj >> 1) & 1, px = jj & 1;
    const float bv = bias[oc];
#pragma unroll
    for (int mi = 0; mi < 8; ++mi) {
      const int y = y0 + wm * 2 + (mi >> 2);
      const int oy = 2 * y + py;
      const int xb = (mi & 3) * 16 + ((lane >> 4) << 2);
      float* orow = out + ((size_t)(n * 256 + oc) * 128 + oy) * 128;
#pragma unroll
      for (int v = 0; v < 4; ++v) {
        orow[2 * (xb + v) + px] = acc[mi][ni][v] + bv;
      }
    }
  }
}

// ---------------- fallback (ws too small): direct, slow, correct ---------------------
__global__ __launch_bounds__(256) void fallback_k(const float* __restrict__ In,
                                                  const float* __restrict__ W,
                                                  const float* __restrict__ bias,
                                                  float* __restrict__ out) {
  const size_t idx = (size_t)blockIdx.x * 256 + threadIdx.x;
  const int ox = (int)(idx & 127), oy = (int)((idx >> 7) & 127);
  const int oc = (int)((idx >> 14) & 255);
  const int n = (int)(idx >> 22);
  const int px = ox & 1, py = oy & 1;
  const int x = ox >> 1, y = oy >> 1;
  float cy[3][3], cx[3][3];
#pragma unroll
  for (int a = 0; a < 3; ++a)
#pragma unroll
    for (int i = 0; i < 3; ++i) {
      cy[a][i] = c_tab[py][a][i];
      cx[a][i] = c_tab[px][a][i];
    }
  float acc = 0.f;
  const float* wbase = W + (size_t)oc * 2304;
  for (int ic = 0; ic < 256; ++ic) {
    const float* ib = In + (((size_t)(n * 256 + ic)) * 64 + y) * 64 + x;
    float pin[3][3];
#pragma unroll
    for (int ay = 0; ay < 3; ++ay) {
      const int yy = y + ay - 1;
#pragma unroll
      for (int ax = 0; ax < 3; ++ax) {
        const int xx = x + ax - 1;
        pin[ay][ax] = (yy >= 0 && yy < 64 && xx >= 0 && xx < 64)
                          ? ib[(ay - 1) * 64 + (ax - 1)] : 0.f;
      }
    }
    const float* w = wbase + ic * 9;
    float U[3][3];
#pragma unroll
    for (int ay = 0; ay < 3; ++ay)
#pragma unroll
      for (int ix = 0; ix < 3; ++ix)
        U[ay][ix] = cx[0][ix] * pin[ay][0] + cx[1][ix] * pin[ay][1] + cx[2][ix] * pin[ay][2];
#pragma unroll
    for (int iy = 0; iy < 3; ++iy)
#pragma unroll
      for (int ix = 0; ix < 3; ++ix) {
        const float V = cy[0][iy] * U[0][ix] + cy[1][iy] * U[1][ix] + cy[2][iy] * U[2][ix];
        acc += w[iy * 3 + ix] * V;
      }
  }
  out[idx] = acc + bias[oc];
}

extern "C" void kernel_launch(void* const* d_in, const int* in_sizes, int n_in,
                              void* d_out, int out_size, void* d_ws, size_t ws_size,
                              hipStream_t stream) {
  const float* In = (const float*)d_in[0];    // [8][256][64][64]
  const float* W = (const float*)d_in[1];     // [256][256][3][3]
  const float* bias = (const float*)d_in[2];  // [256]
  float* out = (float*)d_out;                 // [8][256][128][128]

  const size_t E_BYTES = (size_t)1024 * 2304 * 2;       // 4,718,592
  const size_t A_BYTES = (size_t)8 * 66 * 66 * 256 * 2; // 17,842,176

  if (ws_size >= E_BYTES + A_BYTES) {
    f16* Et = (f16*)d_ws;
    f16* Ah = (f16*)((char*)d_ws + E_BYTES);
    prep_k<<<256 + 4224, 256, 0, stream>>>(W, In, Et, Ah);
    gemm_k<<<512, 512, 0, stream>>>(Ah, Et, bias, out);
  } else {
    fallback_k<<<131072, 256, 0, stream>>>(In, W, bias, out);
  }
}